// Round 13
// baseline (797.795 us; speedup 1.0000x reference)
//
#include <hip/hip_runtime.h>
#include <math.h>

// ---------------- problem constants ----------------
constexpr int NN1 = 65536;      // level-0 nodes
constexpr int EE  = 1048576;    // edges
constexpr int GG  = 64;         // graphs
constexpr int HH  = 128;        // hidden
constexpr int NPG = 1024;       // nodes/graph level-0
constexpr int EPG = 16384;      // edges/graph
constexpr int K1  = 512;        // keep after pool1 (per graph)
constexpr int M1  = GG * K1;    // 32768
constexpr int K2  = 256;        // keep after pool2
constexpr int M2  = GG * K2;    // 16384

// chunked XCD swizzle: XCD x owns the contiguous chunk [x*n/8, (x+1)*n/8) of work.
// Applied to EVERY producer & consumer so each graph's data stays in one XCD's L2.
__device__ __forceinline__ int xcd_swz(int bid, int nblk)
{
    return (bid & 7) * (nblk >> 3) + (bid >> 3);
}

__device__ __forceinline__ float4 f4add(float4 a, float4 b)
{
    a.x += b.x; a.y += b.y; a.z += b.z; a.w += b.w; return a;
}

// ---------------- GEMM v2: spill-proof geometry ----------------
// Lesson from R4/R6/R7/R8: the allocator may squeeze VGPRs to 64 regardless of
// LDS/launch_bounds; any body needing >64 live regs risks a 2.6x spill cliff.
// This body needs ~55 regs -> safe at ANY allocator target.
// Block: 32 rows x 64 cols (blockIdx.y = col half, n0 = y*64). Thread: 2 rows x 8 cols.
// W staged ONCE for all K (128 rows x 64 cols, LDS [128][80] = 40960 B -> 4 blocks/CU,
// 16 waves/CU; R5's 512-block grid gave only 2 waves/SIMD -> 35% VALUBusy).
// Read pattern cg*10: 16 distinct bank residues, max 2-way aliasing (free, m136).
__global__ __launch_bounds__(256) void gemm1_k(const float* __restrict__ A,
                                               const float* __restrict__ W,
                                               const int* __restrict__ rbeg,
                                               const int* __restrict__ rend,
                                               float* __restrict__ C)
{
    __shared__ float Wl[128 * 80];   // 40960 B
    const int t    = threadIdx.x;
    const int cg   = t & 15;         // 0..15, col base cg*4? no: cg*8 within 64? -> cg indexes 8-col groups? 16 groups x 4? 
    // NOTE: 64 cols / 16 col-groups = 4? We use 8 cols/thread -> 8 groups. Use cg=t&7.
    const int cg8  = t & 7;          // 0..7, col base cg8*8 within the 64-col half
    const int rowg = t >> 3;         // 0..31 -> rows rowg and rowg+32? No: 32 rows/block, 2/thread.
    // Mapping: 256 threads = 8 col-groups x 32 row-slots; row r = rowg (0..31), second row handled by... 
    // 32 rows, 2 rows/thread needs 16 row-slots -> use rowg>>1? Simplest: rows r0+rowg for rowg 0..31,
    // each thread owns ONE row pair (rowg, rowg within upper half)? Keep it simple:
    // thread handles rows (r0 + (rowg & 15)) and (r0 + (rowg & 15) + 16); rowg>>4 unused bit folded into cg.
    // To keep 2 rows x 8 cols with 256 threads over 32x64: 16 row-slots x 16 col-... 
    // FINAL mapping (used below): cgf = t & 15 (16 col-groups of 4 cols? no)...
    // --- see actual code: cgA = t & 7 (8 groups x 8 cols), rs = t >> 3 (32 slots), rows rs (1 row!) x 8 cols
    //     would be 1x8. We want 2x8: rs = (t >> 3) & 15 (16 slots), hi = t >> 7 unused...
    const int rs   = t & 0x78;       // placeholder, real mapping below
    (void)cg; (void)rowg; (void)rs;

    // Actual mapping: col-group c8 = t & 7 (8 groups x 8 cols = 64 cols);
    // row-slot    rsl = t >> 3 (0..31); thread covers rows {rsl} only -> that's 1 row x 8 cols = 24 regs.
    // Even MORE squeeze-proof than 2x8, and grid stays the same (rows covered = 32). ILP comes from waves.
    const int c8  = t & 7;
    const int rsl = t >> 3;          // 0..31
    const int bx  = xcd_swz(blockIdx.x, gridDim.x);
    const int n0  = blockIdx.y << 6; // 0 or 64
    const int r   = (bx << 5) + rsl;

    const float* Ar = A + ((size_t)r << 7);

    float acc[8];
#pragma unroll
    for (int j = 0; j < 8; ++j) acc[j] = 0.f;

    // ---- stage W[0:128][n0:n0+64] into Wl[128][80] (2048 float4s, 8/thread) ----
    {
#pragma unroll
        for (int i = 0; i < 8; ++i) {
            int idx = t + (i << 8);          // 0..2047
            int k   = idx >> 4;              // row 0..127
            int c4  = (idx & 15) << 2;       // col 0..60
            float4 v = *(const float4*)(W + k * 128 + n0 + c4);
            *(float4*)&Wl[k * 80 + (c4 >> 3) * 10 + (c4 & 7)] = v;
        }
    }
    float4 xc = *(const float4*)(Ar);
    __syncthreads();

    const float* wb = &Wl[c8 * 10];

#pragma unroll 1
    for (int k0 = 0; k0 < 128; k0 += 4) {
        bool pf = (k0 < 124);
        float4 xn;
        if (pf) xn = *(const float4*)(Ar + k0 + 4);
#pragma unroll
        for (int kk = 0; kk < 4; ++kk) {
            const float* wr = wb + (k0 + kk) * 80;
            float wv[8];
            *(float4*)&wv[0] = *(const float4*)(wr);
            *(float4*)&wv[4] = *(const float4*)(wr + 4);
            float xv = ((const float*)&xc)[kk];
#pragma unroll
            for (int j = 0; j < 8; ++j) acc[j] = fmaf(xv, wv[j], acc[j]);
        }
        if (pf) xc = xn;
    }

    // epilogue: scale by dinv[r] = 1/sqrt(deg+1), write 8 cols
    {
        float deg = (float)(rend[r] - rbeg[r]) + 1.0f;
        float sc = 1.0f / sqrtf(deg);
        float* cp = C + ((size_t)r << 7) + n0 + (c8 << 3);
        float4 v0, v1;
        v0.x = acc[0] * sc; v0.y = acc[1] * sc; v0.z = acc[2] * sc; v0.w = acc[3] * sc;
        v1.x = acc[4] * sc; v1.y = acc[5] * sc; v1.z = acc[6] * sc; v1.w = acc[7] * sc;
        *(float4*)(cp) = v0;
        *(float4*)(cp + 4) = v1;
    }
}

// ---------------- GEMM v2 level 2: row via perm, scale *= tsel ----------------
__global__ __launch_bounds__(256) void gemm2_k(const float* __restrict__ A,
                                               const float* __restrict__ W,
                                               const int* __restrict__ rbeg,
                                               const int* __restrict__ rend,
                                               const int* __restrict__ perm,
                                               const float* __restrict__ tsel,
                                               float* __restrict__ C)
{
    __shared__ float Wl[128 * 80];   // 40960 B
    const int t   = threadIdx.x;
    const int c8  = t & 7;
    const int rsl = t >> 3;          // 0..31
    const int bx  = xcd_swz(blockIdx.x, gridDim.x);
    const int n0  = blockIdx.y << 6;
    const int r   = (bx << 5) + rsl;

    const float* Ar = A + ((size_t)perm[r] << 7);

    float acc[8];
#pragma unroll
    for (int j = 0; j < 8; ++j) acc[j] = 0.f;

    {
#pragma unroll
        for (int i = 0; i < 8; ++i) {
            int idx = t + (i << 8);
            int k   = idx >> 4;
            int c4  = (idx & 15) << 2;
            float4 v = *(const float4*)(W + k * 128 + n0 + c4);
            *(float4*)&Wl[k * 80 + (c4 >> 3) * 10 + (c4 & 7)] = v;
        }
    }
    float4 xc = *(const float4*)(Ar);
    __syncthreads();

    const float* wb = &Wl[c8 * 10];

#pragma unroll 1
    for (int k0 = 0; k0 < 128; k0 += 4) {
        bool pf = (k0 < 124);
        float4 xn;
        if (pf) xn = *(const float4*)(Ar + k0 + 4);
#pragma unroll
        for (int kk = 0; kk < 4; ++kk) {
            const float* wr = wb + (k0 + kk) * 80;
            float wv[8];
            *(float4*)&wv[0] = *(const float4*)(wr);
            *(float4*)&wv[4] = *(const float4*)(wr + 4);
            float xv = ((const float*)&xc)[kk];
#pragma unroll
            for (int j = 0; j < 8; ++j) acc[j] = fmaf(xv, wv[j], acc[j]);
        }
        if (pf) xc = xn;
    }

    {
        float deg = (float)(rend[r] - rbeg[r]) + 1.0f;
        float sc = tsel[r] / sqrtf(deg);
        float* cp = C + ((size_t)r << 7) + n0 + (c8 << 3);
        float4 v0, v1;
        v0.x = acc[0] * sc; v0.y = acc[1] * sc; v0.z = acc[2] * sc; v0.w = acc[3] * sc;
        v1.x = acc[4] * sc; v1.y = acc[5] * sc; v1.z = acc[6] * sc; v1.w = acc[7] * sc;
        *(float4*)(cp) = v0;
        *(float4*)(cp + 4) = v1;
    }
}

// ---------------- per-graph CSR build, level 1 (count+scan+fill in one block) ----------
__global__ __launch_bounds__(1024) void build_csr1_k(const int* __restrict__ src, const int* __restrict__ dst,
                                                     int* __restrict__ rbeg, int* __restrict__ rend,
                                                     int* __restrict__ csr)
{
    __shared__ int cnt[NPG];
    int t = threadIdx.x;
    int g = xcd_swz(blockIdx.x, GG);
    int ebase = g * EPG;
    cnt[t] = 0;
    __syncthreads();
#pragma unroll
    for (int k = 0; k < EPG / 1024; ++k) {
        int d = dst[ebase + t + k * 1024] & (NPG - 1);
        atomicAdd(&cnt[d], 1);
    }
    __syncthreads();
    int deg0 = cnt[t];
    int val = deg0;
    for (int off = 1; off < NPG; off <<= 1) {
        int u = (t >= off) ? cnt[t - off] : 0;
        __syncthreads();
        val += u; cnt[t] = val;
        __syncthreads();
    }
    int node = g * NPG + t;
    rbeg[node] = ebase + val - deg0;
    rend[node] = ebase + val;
    cnt[t] = val - deg0;
    __syncthreads();
#pragma unroll
    for (int k = 0; k < EPG / 1024; ++k) {
        int e = ebase + t + k * 1024;
        int d = dst[e] & (NPG - 1);
        int pos = atomicAdd(&cnt[d], 1);
        csr[ebase + pos] = src[e];
    }
}

// ---------------- GCN aggregation over prescaled rows, fused bias+relu+score-projection ----
__global__ __launch_bounds__(256) void agg_feat_k(const float4* __restrict__ XWs,
                                                  const int* __restrict__ rbeg, const int* __restrict__ rend,
                                                  const int* __restrict__ csr,
                                                  const float* __restrict__ bias, const float* __restrict__ Ws,
                                                  float* __restrict__ hout, float* __restrict__ hss, int n)
{
    int b    = xcd_swz(blockIdx.x, gridDim.x);
    int half = threadIdx.x >> 5;
    int lane = threadIdx.x & 31;
    int node = (b << 3) + half;
    if (node >= n) return;
    const float4* Xf = XWs + lane;              // row r at Xf[r*32]

    float4 A = make_float4(0.f, 0.f, 0.f, 0.f), B = A, C = A, D = A;
    int p0 = rbeg[node], p1 = rend[node];
    int p = p0;
    for (; p + 8 <= p1; p += 8) {
        int s0 = csr[p], s1 = csr[p + 1], s2 = csr[p + 2], s3 = csr[p + 3];
        int s4 = csr[p + 4], s5 = csr[p + 5], s6 = csr[p + 6], s7 = csr[p + 7];
        float4 v0 = Xf[(size_t)s0 << 5], v1 = Xf[(size_t)s1 << 5];
        float4 v2 = Xf[(size_t)s2 << 5], v3 = Xf[(size_t)s3 << 5];
        float4 v4 = Xf[(size_t)s4 << 5], v5 = Xf[(size_t)s5 << 5];
        float4 v6 = Xf[(size_t)s6 << 5], v7 = Xf[(size_t)s7 << 5];
        A = f4add(A, v0); B = f4add(B, v1); C = f4add(C, v2); D = f4add(D, v3);
        A = f4add(A, v4); B = f4add(B, v5); C = f4add(C, v6); D = f4add(D, v7);
    }
    for (; p + 4 <= p1; p += 4) {
        int s0 = csr[p], s1 = csr[p + 1], s2 = csr[p + 2], s3 = csr[p + 3];
        float4 v0 = Xf[(size_t)s0 << 5], v1 = Xf[(size_t)s1 << 5];
        float4 v2 = Xf[(size_t)s2 << 5], v3 = Xf[(size_t)s3 << 5];
        A = f4add(A, v0); B = f4add(B, v1); C = f4add(C, v2); D = f4add(D, v3);
    }
    for (; p < p1; ++p) {
        int s = csr[p];
        A = f4add(A, Xf[(size_t)s << 5]);
    }
    float4 acc = f4add(f4add(A, B), f4add(C, D));
    acc = f4add(acc, Xf[(size_t)node << 5]);    // self term (prescaled)

    float dd = 1.0f / sqrtf((float)(p1 - p0) + 1.0f);
    float4 bb = *(const float4*)(bias + (lane << 2));
    acc.x = fmaxf(fmaf(acc.x, dd, bb.x), 0.f);
    acc.y = fmaxf(fmaf(acc.y, dd, bb.y), 0.f);
    acc.z = fmaxf(fmaf(acc.z, dd, bb.z), 0.f);
    acc.w = fmaxf(fmaf(acc.w, dd, bb.w), 0.f);
    *(float4*)(hout + ((size_t)node << 7) + (lane << 2)) = acc;

    float4 wsv = *(const float4*)(Ws + (lane << 2));
    float pq = acc.x * wsv.x + acc.y * wsv.y + acc.z * wsv.z + acc.w * wsv.w;
#pragma unroll
    for (int off = 16; off > 0; off >>= 1) pq += __shfl_down(pq, off, 32);
    if (lane == 0) hss[node] = dd * pq;         // prescaled score
}

// ---- fused score + top-k + (BUILD: level-2 CSR) + per-graph readout {max|mean} --------
template <int NNE, int KK, bool BUILD>
__global__ void sctopk_k(const int* __restrict__ rbeg, const int* __restrict__ rend,
                         const int* __restrict__ csr, const float* __restrict__ hss,
                         const float* __restrict__ bsp,
                         int* __restrict__ perm, float* __restrict__ tsel,
                         const int* __restrict__ src, const int* __restrict__ dst,
                         int* __restrict__ rbeg2, int* __restrict__ rend2,
                         int* __restrict__ csr2,
                         const float* __restrict__ h, float* __restrict__ xout)
{
    __shared__ unsigned long long keys[NNE];
    __shared__ float hl[NNE];
    __shared__ int   pix[KK];
    __shared__ float tsl[KK];
    int t = threadIdx.x;
    int g = xcd_swz(blockIdx.x, GG);
    int node = g * NNE + t;
    hl[t] = hss[node];
    __syncthreads();

    // ---- score: gather prescaled neighbor scores from LDS ----
    int p0 = rbeg[node], p1 = rend[node];
    float a = 0.f, b = 0.f, c = 0.f, e = 0.f;
    int p = p0;
    for (; p + 8 <= p1; p += 8) {
        int s0 = csr[p] & (NNE - 1), s1 = csr[p + 1] & (NNE - 1);
        int s2 = csr[p + 2] & (NNE - 1), s3 = csr[p + 3] & (NNE - 1);
        int s4 = csr[p + 4] & (NNE - 1), s5 = csr[p + 5] & (NNE - 1);
        int s6 = csr[p + 6] & (NNE - 1), s7 = csr[p + 7] & (NNE - 1);
        a += hl[s0]; b += hl[s1]; c += hl[s2]; e += hl[s3];
        a += hl[s4]; b += hl[s5]; c += hl[s6]; e += hl[s7];
    }
    for (; p + 4 <= p1; p += 4) {
        int s0 = csr[p] & (NNE - 1), s1 = csr[p + 1] & (NNE - 1);
        int s2 = csr[p + 2] & (NNE - 1), s3 = csr[p + 3] & (NNE - 1);
        a += hl[s0]; b += hl[s1]; c += hl[s2]; e += hl[s3];
    }
    for (; p < p1; ++p) a += hl[csr[p] & (NNE - 1)];
    float dd = 1.0f / sqrtf((float)(p1 - p0) + 1.0f);
    float s = fmaf((a + b) + (c + e) + hl[t], dd, bsp[0]);

    // ---- bitonic sort of (monotone score, NNE-1-idx): exact jax top_k tie-break ----
    unsigned u = __float_as_uint(s);
    u = (u & 0x80000000u) ? ~u : (u | 0x80000000u);
    __syncthreads();
    keys[t] = (((unsigned long long)u) << 32) | (unsigned)(NNE - 1 - t);
    __syncthreads();
    for (int k = 2; k <= NNE; k <<= 1) {
        for (int j = k >> 1; j > 0; j >>= 1) {
            int ixj = t ^ j;
            if (ixj > t) {
                unsigned long long ka = keys[t], kb = keys[ixj];
                bool up = ((t & k) == 0);
                if ((ka > kb) == up) { keys[t] = kb; keys[ixj] = ka; }
            }
            __syncthreads();
        }
    }
    unsigned long long key = keys[NNE - 1 - t];   // rank t
    int idx = NNE - 1 - (int)(key & 0xFFFFFFFFu);
    if (t < KK) {
        unsigned uu = (unsigned)(key >> 32);
        float sc = __uint_as_float((uu & 0x80000000u) ? (uu ^ 0x80000000u) : ~uu);
        float tv = tanhf(sc);
        pix[t] = g * NNE + idx;
        tsl[t] = tv;
        if (BUILD) {                   // level 1: gemm2 consumes these globally
            perm[g * KK + t] = g * NNE + idx;
            tsel[g * KK + t] = tv;
        }
    }

    if (BUILD) {
        constexpr int EPT = BUILD ? (EPG / NNE) : 1;
        __syncthreads();                       // all keys reads done -> regions reusable
        int* nml = (int*)hl;                   // local new-id map (NNE ints)
        int* cnt = (int*)keys;                 // KK counters
        nml[t] = -1;
        if (t < KK) cnt[t] = 0;
        __syncthreads();
        if (t < KK) nml[idx] = t;              // local rank of kept node
        __syncthreads();

        int ebase = g * EPG;
        int nsl[EPT], ndl[EPT];
#pragma unroll
        for (int k = 0; k < EPT; ++k) {
            int e = ebase + t + k * NNE;
            nsl[k] = nml[src[e] & (NNE - 1)];
            ndl[k] = nml[dst[e] & (NNE - 1)];
            if (nsl[k] >= 0 && ndl[k] >= 0) atomicAdd(&cnt[ndl[k]], 1);
        }
        __syncthreads();
        int deg0 = 0, val = 0;
        if (t < KK) { deg0 = cnt[t]; val = deg0; }
        for (int off = 1; off < KK; off <<= 1) {
            int u2 = (t < KK && t >= off) ? cnt[t - off] : 0;
            __syncthreads();
            if (t < KK) { val += u2; cnt[t] = val; }
            __syncthreads();
        }
        if (t < KK) {
            int n2 = g * KK + t;
            rbeg2[n2] = ebase + val - deg0;
            rend2[n2] = ebase + val;
            cnt[t] = val - deg0;
        }
        __syncthreads();
#pragma unroll
        for (int k = 0; k < EPT; ++k) {
            if (nsl[k] >= 0 && ndl[k] >= 0) {
                int pos = atomicAdd(&cnt[ndl[k]], 1);
                csr2[ebase + pos] = g * KK + nsl[k];
            }
        }
    }

    // ---- readout: x[g] = {col-max | col-mean} over KK kept rows of h*tanh ----
    constexpr int G = NNE / 128;               // row groups
    __syncthreads();                           // cnt/keys last use done
    float* rmax = (float*)keys;                // [G][128]
    float* rsum = rmax + G * 128;              // [G][128]  (2*G*128*4 == 8*NNE bytes)
    int col = t & 127;
    int grp = t >> 7;
    float mx = -INFINITY, sm = 0.f;
#pragma unroll 8
    for (int rr0 = 0; rr0 < KK / G; ++rr0) {
        int rr = grp + rr0 * G;
        int o = pix[rr];
        float tv = tsl[rr];
        float v = h[((size_t)o << 7) + col] * tv;
        mx = fmaxf(mx, v);
        sm += v;
    }
    rmax[grp * 128 + col] = mx;
    rsum[grp * 128 + col] = sm;
    __syncthreads();
    if (t < 128) {
        float m = rmax[t], s2 = rsum[t];
#pragma unroll
        for (int j2 = 1; j2 < G; ++j2) {
            m = fmaxf(m, rmax[j2 * 128 + t]);
            s2 += rsum[j2 * 128 + t];
        }
        xout[g * 256 + t] = m;
        xout[g * 256 + 128 + t] = s2 * (1.0f / (float)KK);
    }
}

// ---------------- head: z=x1+x2; relu(z@Wl1+bl1); @Wl2+bl2 ------------
__global__ __launch_bounds__(128) void mlp_k(const float* __restrict__ x1, const float* __restrict__ x2,
                                             const float* __restrict__ Wl1, const float* __restrict__ bl1,
                                             const float* __restrict__ Wl2, const float* __restrict__ bl2,
                                             float* __restrict__ out)
{
    __shared__ float z[256];
    __shared__ float red[128];
    int g = blockIdx.x, t = threadIdx.x;
    z[t]       = x1[g * 256 + t]       + x2[g * 256 + t];
    z[t + 128] = x1[g * 256 + 128 + t] + x2[g * 256 + 128 + t];
    __syncthreads();
    float acc = bl1[t];
    for (int k = 0; k < 256; ++k) acc = fmaf(z[k], Wl1[k * 128 + t], acc);
    float zz = fmaxf(acc, 0.f);
    red[t] = zz * Wl2[t];
    __syncthreads();
    for (int off = 64; off > 0; off >>= 1) {
        if (t < off) red[t] += red[t + off];
        __syncthreads();
    }
    if (t == 0) out[g] = red[0] + bl2[0];
}

// ---------------- launch ----------------
extern "C" void kernel_launch(void* const* d_in, const int* in_sizes, int n_in,
                              void* d_out, int out_size, void* d_ws, size_t ws_size,
                              hipStream_t stream)
{
    const float* x   = (const float*)d_in[0];
    const int*   src = (const int*)d_in[1];
    const int*   dst = (const int*)d_in[2];
    const float* W1  = (const float*)d_in[3];
    const float* b1  = (const float*)d_in[4];
    const float* Ws1 = (const float*)d_in[5];
    const float* bs1 = (const float*)d_in[6];
    const float* W2  = (const float*)d_in[7];
    const float* b2  = (const float*)d_in[8];
    const float* Ws2 = (const float*)d_in[9];
    const float* bs2 = (const float*)d_in[10];
    const float* Wl1 = (const float*)d_in[11];
    const float* bl1 = (const float*)d_in[12];
    const float* Wl2 = (const float*)d_in[13];
    const float* bl2 = (const float*)d_in[14];
    float* out = (float*)d_out;
    char* ws = (char*)d_ws;

    // big regions (time-multiplexed)
    float* XW1 = (float*)(ws);                        // 32MB [0,32M)   (dinv-prescaled)
    float* h1  = (float*)(ws + ((size_t)32 << 20));   // 32MB [32M,64M)
    float* XW2 = (float*)(ws);                        // 16MB [0,16M)   (XW1 dead after agg1)
    float* h2  = (float*)(ws + ((size_t)16 << 20));   // 16MB [16M,32M)
    size_t SB = (size_t)64 << 20;
    auto alloc = [&](size_t bytes) { char* p = ws + SB; SB += (bytes + 255) & ~(size_t)255; return p; };
    int* csr1     = (int*)alloc((size_t)EE * 4);      // reused as csr2 (in-block, race-free)
    int* rbeg1    = (int*)alloc(NN1 * 4);
    int* rend1    = (int*)alloc(NN1 * 4);
    float* hss1   = (float*)alloc(NN1 * 4);
    int* perm1    = (int*)alloc(M1 * 4);
    float* tsel1  = (float*)alloc(M1 * 4);
    int* rbeg2    = (int*)alloc(M1 * 4);
    int* rend2    = (int*)alloc(M1 * 4);
    float* hss2   = (float*)alloc(M1 * 4);
    float* x1b    = (float*)alloc(GG * 256 * 4);
    float* x2b    = (float*)alloc(GG * 256 * 4);
    int* csr2     = csr1;
    (void)ws_size; (void)in_sizes; (void)n_in; (void)out_size;

    // ---- level 1 ----
    build_csr1_k<<<GG, 1024, 0, stream>>>(src, dst, rbeg1, rend1, csr1);
    gemm1_k<<<dim3(NN1 / 32, 2), 256, 0, stream>>>(x, W1, rbeg1, rend1, XW1);
    agg_feat_k<<<NN1 / 8, 256, 0, stream>>>((const float4*)XW1, rbeg1, rend1, csr1, b1, Ws1, h1, hss1, NN1);
    sctopk_k<NPG, K1, true><<<GG, NPG, 0, stream>>>(rbeg1, rend1, csr1, hss1, bs1, perm1, tsel1,
                                                    src, dst, rbeg2, rend2, csr2, h1, x1b);
    // ---- level 2 ----
    gemm2_k<<<dim3(M1 / 32, 2), 256, 0, stream>>>(h1, W2, rbeg2, rend2, perm1, tsel1, XW2);
    agg_feat_k<<<M1 / 8, 256, 0, stream>>>((const float4*)XW2, rbeg2, rend2, csr2, b2, Ws2, h2, hss2, M1);
    sctopk_k<K1, K2, false><<<GG, K1, 0, stream>>>(rbeg2, rend2, csr2, hss2, bs2, nullptr, nullptr,
                                                   nullptr, nullptr, nullptr, nullptr, nullptr, h2, x2b);
    // ---- head ----
    mlp_k<<<GG, 128, 0, stream>>>(x1b, x2b, Wl1, bl1, Wl2, bl2, out);
}

// Round 14
// 186.723 us; speedup vs baseline: 4.2726x; 4.2726x over previous
//
#include <hip/hip_runtime.h>
#include <math.h>

// ---------------- problem constants ----------------
constexpr int NN1 = 65536;      // level-0 nodes
constexpr int EE  = 1048576;    // edges
constexpr int GG  = 64;         // graphs
constexpr int HH  = 128;        // hidden
constexpr int NPG = 1024;       // nodes/graph level-0
constexpr int EPG = 16384;      // edges/graph
constexpr int K1  = 512;        // keep after pool1 (per graph)
constexpr int M1  = GG * K1;    // 32768
constexpr int K2  = 256;        // keep after pool2
constexpr int M2  = GG * K2;    // 16384

// chunked XCD swizzle: XCD x owns the contiguous chunk [x*n/8, (x+1)*n/8) of work.
// Applied to EVERY producer & consumer so each graph's data stays in one XCD's L2.
__device__ __forceinline__ int xcd_swz(int bid, int nblk)
{
    return (bid & 7) * (nblk >> 3) + (bid >> 3);
}

__device__ __forceinline__ float4 f4add(float4 a, float4 b)
{
    a.x += b.x; a.y += b.y; a.z += b.z; a.w += b.w; return a;
}

// ---------------- GEMM (level 1): C[r] = dinv[r] * (A[r] @ W)  ----------------
// FROZEN. EXACT R5 geometry (measured: VGPR 76, no spill, 47.5us): 256 threads,
// block tile 128 rows x 128 cols, thread 4 rows x 16 cols; W in two 64-row LDS
// chunks (40960 B, row stride 160, col-group cg*20 -> perfect 32-bank partition,
// 0.25 LDS-floats/FMA); A loads software-pipelined through named registers.
// Re-geometry attempts ALL regressed: R6 512thr (126us, VGPR squeeze->spill),
// R7 512thr+fullW (125us, same), R8 256thr 4x8 (126us), R13 1x8 thread tile
// (457us: 1.0 LDS-floats/FMA = 4x LDS demand -> LDS-throughput-bound, VALU 4.5%).
__global__ __launch_bounds__(256) void gemm1_k(const float* __restrict__ A,
                                               const float* __restrict__ W,
                                               const int* __restrict__ rbeg,
                                               const int* __restrict__ rend,
                                               float* __restrict__ C)
{
    __shared__ float Wl[64 * 160];   // 40960 B
    const int t    = threadIdx.x;
    const int rowg = t >> 3;         // 0..31
    const int cg   = t & 7;          // 0..7
    const int b    = xcd_swz(blockIdx.x, gridDim.x);
    const int r0   = (b << 7) + rowg;

    const float* Ar0 = A + ((size_t)r0 << 7);
    const float* Ar1 = Ar0 + (32 << 7);
    const float* Ar2 = Ar1 + (32 << 7);
    const float* Ar3 = Ar2 + (32 << 7);

    float acc[4][16];
#pragma unroll
    for (int i = 0; i < 4; ++i)
#pragma unroll
        for (int j = 0; j < 16; ++j) acc[i][j] = 0.f;

    // ---- stage chunk 0 ----
    {
        const float4* Wg = (const float4*)W;
#pragma unroll
        for (int i = 0; i < 8; ++i) {
            int idx = t + (i << 8);
            int k   = idx >> 5;
            int c4  = (idx & 31) << 2;
            *(float4*)&Wl[k * 160 + (c4 >> 4) * 20 + (c4 & 15)] = Wg[idx];
        }
    }
    float4 xc0 = *(const float4*)(Ar0), xc1 = *(const float4*)(Ar1);
    float4 xc2 = *(const float4*)(Ar2), xc3 = *(const float4*)(Ar3);
    __syncthreads();

    const float* wbase = &Wl[cg * 20];

#pragma unroll 1
    for (int k0 = 0; k0 < 64; k0 += 4) {
        float4 xn0 = *(const float4*)(Ar0 + k0 + 4);
        float4 xn1 = *(const float4*)(Ar1 + k0 + 4);
        float4 xn2 = *(const float4*)(Ar2 + k0 + 4);
        float4 xn3 = *(const float4*)(Ar3 + k0 + 4);
#pragma unroll
        for (int kk = 0; kk < 4; ++kk) {
            const float* wr = wbase + (k0 + kk) * 160;
            float x0 = ((const float*)&xc0)[kk], x1 = ((const float*)&xc1)[kk];
            float x2 = ((const float*)&xc2)[kk], x3 = ((const float*)&xc3)[kk];
#pragma unroll
            for (int jh = 0; jh < 16; jh += 8) {
                float wv[8];
                *(float4*)&wv[0] = *(const float4*)(wr + jh);
                *(float4*)&wv[4] = *(const float4*)(wr + jh + 4);
#pragma unroll
                for (int j = 0; j < 8; ++j) {
                    acc[0][jh + j] = fmaf(x0, wv[j], acc[0][jh + j]);
                    acc[1][jh + j] = fmaf(x1, wv[j], acc[1][jh + j]);
                    acc[2][jh + j] = fmaf(x2, wv[j], acc[2][jh + j]);
                    acc[3][jh + j] = fmaf(x3, wv[j], acc[3][jh + j]);
                }
            }
        }
        xc0 = xn0; xc1 = xn1; xc2 = xn2; xc3 = xn3;
    }
    __syncthreads();
    // ---- stage chunk 1 ----
    {
        const float4* Wg = (const float4*)(W + 64 * 128);
#pragma unroll
        for (int i = 0; i < 8; ++i) {
            int idx = t + (i << 8);
            int k   = idx >> 5;
            int c4  = (idx & 31) << 2;
            *(float4*)&Wl[k * 160 + (c4 >> 4) * 20 + (c4 & 15)] = Wg[idx];
        }
    }
    __syncthreads();

#pragma unroll 1
    for (int k0 = 64; k0 < 128; k0 += 4) {
        bool pf = (k0 < 124);
        float4 xn0, xn1, xn2, xn3;
        if (pf) {
            xn0 = *(const float4*)(Ar0 + k0 + 4);
            xn1 = *(const float4*)(Ar1 + k0 + 4);
            xn2 = *(const float4*)(Ar2 + k0 + 4);
            xn3 = *(const float4*)(Ar3 + k0 + 4);
        }
#pragma unroll
        for (int kk = 0; kk < 4; ++kk) {
            const float* wr = wbase + (k0 - 64 + kk) * 160;
            float x0 = ((const float*)&xc0)[kk], x1 = ((const float*)&xc1)[kk];
            float x2 = ((const float*)&xc2)[kk], x3 = ((const float*)&xc3)[kk];
#pragma unroll
            for (int jh = 0; jh < 16; jh += 8) {
                float wv[8];
                *(float4*)&wv[0] = *(const float4*)(wr + jh);
                *(float4*)&wv[4] = *(const float4*)(wr + jh + 4);
#pragma unroll
                for (int j = 0; j < 8; ++j) {
                    acc[0][jh + j] = fmaf(x0, wv[j], acc[0][jh + j]);
                    acc[1][jh + j] = fmaf(x1, wv[j], acc[1][jh + j]);
                    acc[2][jh + j] = fmaf(x2, wv[j], acc[2][jh + j]);
                    acc[3][jh + j] = fmaf(x3, wv[j], acc[3][jh + j]);
                }
            }
        }
        if (pf) { xc0 = xn0; xc1 = xn1; xc2 = xn2; xc3 = xn3; }
    }

    // epilogue: scale by dinv[r] = 1/sqrt(deg+1), write
#pragma unroll
    for (int i = 0; i < 4; ++i) {
        int r = r0 + (i << 5);
        float deg = (float)(rend[r] - rbeg[r]) + 1.0f;
        float sc = 1.0f / sqrtf(deg);
        float* cp = C + ((size_t)r << 7) + (cg << 4);
#pragma unroll
        for (int j = 0; j < 16; j += 4) {
            float4 v;
            v.x = acc[i][j] * sc; v.y = acc[i][j + 1] * sc;
            v.z = acc[i][j + 2] * sc; v.w = acc[i][j + 3] * sc;
            *(float4*)(cp + j) = v;
        }
    }
}

// ---------------- GEMM (level 2): C[r] = dinv2[r]*tsel[r] * (A[perm[r]] @ W) ------------
// FROZEN (same body as gemm1_k; row sources via perm, tsel folded into epilogue).
__global__ __launch_bounds__(256) void gemm2_k(const float* __restrict__ A,
                                               const float* __restrict__ W,
                                               const int* __restrict__ rbeg,
                                               const int* __restrict__ rend,
                                               const int* __restrict__ perm,
                                               const float* __restrict__ tsel,
                                               float* __restrict__ C)
{
    __shared__ float Wl[64 * 160];   // 40960 B
    const int t    = threadIdx.x;
    const int rowg = t >> 3;         // 0..31
    const int cg   = t & 7;          // 0..7
    const int b    = xcd_swz(blockIdx.x, gridDim.x);
    const int r0   = (b << 7) + rowg;

    const float* Ar0 = A + ((size_t)perm[r0] << 7);
    const float* Ar1 = A + ((size_t)perm[r0 + 32] << 7);
    const float* Ar2 = A + ((size_t)perm[r0 + 64] << 7);
    const float* Ar3 = A + ((size_t)perm[r0 + 96] << 7);

    float acc[4][16];
#pragma unroll
    for (int i = 0; i < 4; ++i)
#pragma unroll
        for (int j = 0; j < 16; ++j) acc[i][j] = 0.f;

    {
        const float4* Wg = (const float4*)W;
#pragma unroll
        for (int i = 0; i < 8; ++i) {
            int idx = t + (i << 8);
            int k   = idx >> 5;
            int c4  = (idx & 31) << 2;
            *(float4*)&Wl[k * 160 + (c4 >> 4) * 20 + (c4 & 15)] = Wg[idx];
        }
    }
    float4 xc0 = *(const float4*)(Ar0), xc1 = *(const float4*)(Ar1);
    float4 xc2 = *(const float4*)(Ar2), xc3 = *(const float4*)(Ar3);
    __syncthreads();

    const float* wbase = &Wl[cg * 20];

#pragma unroll 1
    for (int k0 = 0; k0 < 64; k0 += 4) {
        float4 xn0 = *(const float4*)(Ar0 + k0 + 4);
        float4 xn1 = *(const float4*)(Ar1 + k0 + 4);
        float4 xn2 = *(const float4*)(Ar2 + k0 + 4);
        float4 xn3 = *(const float4*)(Ar3 + k0 + 4);
#pragma unroll
        for (int kk = 0; kk < 4; ++kk) {
            const float* wr = wbase + (k0 + kk) * 160;
            float x0 = ((const float*)&xc0)[kk], x1 = ((const float*)&xc1)[kk];
            float x2 = ((const float*)&xc2)[kk], x3 = ((const float*)&xc3)[kk];
#pragma unroll
            for (int jh = 0; jh < 16; jh += 8) {
                float wv[8];
                *(float4*)&wv[0] = *(const float4*)(wr + jh);
                *(float4*)&wv[4] = *(const float4*)(wr + jh + 4);
#pragma unroll
                for (int j = 0; j < 8; ++j) {
                    acc[0][jh + j] = fmaf(x0, wv[j], acc[0][jh + j]);
                    acc[1][jh + j] = fmaf(x1, wv[j], acc[1][jh + j]);
                    acc[2][jh + j] = fmaf(x2, wv[j], acc[2][jh + j]);
                    acc[3][jh + j] = fmaf(x3, wv[j], acc[3][jh + j]);
                }
            }
        }
        xc0 = xn0; xc1 = xn1; xc2 = xn2; xc3 = xn3;
    }
    __syncthreads();
    {
        const float4* Wg = (const float4*)(W + 64 * 128);
#pragma unroll
        for (int i = 0; i < 8; ++i) {
            int idx = t + (i << 8);
            int k   = idx >> 5;
            int c4  = (idx & 31) << 2;
            *(float4*)&Wl[k * 160 + (c4 >> 4) * 20 + (c4 & 15)] = Wg[idx];
        }
    }
    __syncthreads();

#pragma unroll 1
    for (int k0 = 64; k0 < 128; k0 += 4) {
        bool pf = (k0 < 124);
        float4 xn0, xn1, xn2, xn3;
        if (pf) {
            xn0 = *(const float4*)(Ar0 + k0 + 4);
            xn1 = *(const float4*)(Ar1 + k0 + 4);
            xn2 = *(const float4*)(Ar2 + k0 + 4);
            xn3 = *(const float4*)(Ar3 + k0 + 4);
        }
#pragma unroll
        for (int kk = 0; kk < 4; ++kk) {
            const float* wr = wbase + (k0 - 64 + kk) * 160;
            float x0 = ((const float*)&xc0)[kk], x1 = ((const float*)&xc1)[kk];
            float x2 = ((const float*)&xc2)[kk], x3 = ((const float*)&xc3)[kk];
#pragma unroll
            for (int jh = 0; jh < 16; jh += 8) {
                float wv[8];
                *(float4*)&wv[0] = *(const float4*)(wr + jh);
                *(float4*)&wv[4] = *(const float4*)(wr + jh + 4);
#pragma unroll
                for (int j = 0; j < 8; ++j) {
                    acc[0][jh + j] = fmaf(x0, wv[j], acc[0][jh + j]);
                    acc[1][jh + j] = fmaf(x1, wv[j], acc[1][jh + j]);
                    acc[2][jh + j] = fmaf(x2, wv[j], acc[2][jh + j]);
                    acc[3][jh + j] = fmaf(x3, wv[j], acc[3][jh + j]);
                }
            }
        }
        if (pf) { xc0 = xn0; xc1 = xn1; xc2 = xn2; xc3 = xn3; }
    }

#pragma unroll
    for (int i = 0; i < 4; ++i) {
        int r = r0 + (i << 5);
        float deg = (float)(rend[r] - rbeg[r]) + 1.0f;
        float sc = tsel[r] / sqrtf(deg);
        float* cp = C + ((size_t)r << 7) + (cg << 4);
#pragma unroll
        for (int j = 0; j < 16; j += 4) {
            float4 v;
            v.x = acc[i][j] * sc; v.y = acc[i][j + 1] * sc;
            v.z = acc[i][j + 2] * sc; v.w = acc[i][j + 3] * sc;
            *(float4*)(cp + j) = v;
        }
    }
}

// ---------------- per-graph CSR build, level 1 (count+scan+fill in one block) ----------
__global__ __launch_bounds__(1024) void build_csr1_k(const int* __restrict__ src, const int* __restrict__ dst,
                                                     int* __restrict__ rbeg, int* __restrict__ rend,
                                                     int* __restrict__ csr)
{
    __shared__ int cnt[NPG];
    int t = threadIdx.x;
    int g = xcd_swz(blockIdx.x, GG);
    int ebase = g * EPG;
    cnt[t] = 0;
    __syncthreads();
#pragma unroll
    for (int k = 0; k < EPG / 1024; ++k) {
        int d = dst[ebase + t + k * 1024] & (NPG - 1);
        atomicAdd(&cnt[d], 1);
    }
    __syncthreads();
    int deg0 = cnt[t];
    int val = deg0;
    for (int off = 1; off < NPG; off <<= 1) {
        int u = (t >= off) ? cnt[t - off] : 0;
        __syncthreads();
        val += u; cnt[t] = val;
        __syncthreads();
    }
    int node = g * NPG + t;
    rbeg[node] = ebase + val - deg0;
    rend[node] = ebase + val;
    cnt[t] = val - deg0;
    __syncthreads();
#pragma unroll
    for (int k = 0; k < EPG / 1024; ++k) {
        int e = ebase + t + k * 1024;
        int d = dst[e] & (NPG - 1);
        int pos = atomicAdd(&cnt[d], 1);
        csr[ebase + pos] = src[e];
    }
}

// ---------------- GCN aggregation over prescaled rows, fused bias+relu+score-projection ----
__global__ __launch_bounds__(256) void agg_feat_k(const float4* __restrict__ XWs,
                                                  const int* __restrict__ rbeg, const int* __restrict__ rend,
                                                  const int* __restrict__ csr,
                                                  const float* __restrict__ bias, const float* __restrict__ Ws,
                                                  float* __restrict__ hout, float* __restrict__ hss, int n)
{
    int b    = xcd_swz(blockIdx.x, gridDim.x);
    int half = threadIdx.x >> 5;
    int lane = threadIdx.x & 31;
    int node = (b << 3) + half;
    if (node >= n) return;
    const float4* Xf = XWs + lane;              // row r at Xf[r*32]

    float4 A = make_float4(0.f, 0.f, 0.f, 0.f), B = A, C = A, D = A;
    int p0 = rbeg[node], p1 = rend[node];
    int p = p0;
    for (; p + 8 <= p1; p += 8) {
        int s0 = csr[p], s1 = csr[p + 1], s2 = csr[p + 2], s3 = csr[p + 3];
        int s4 = csr[p + 4], s5 = csr[p + 5], s6 = csr[p + 6], s7 = csr[p + 7];
        float4 v0 = Xf[(size_t)s0 << 5], v1 = Xf[(size_t)s1 << 5];
        float4 v2 = Xf[(size_t)s2 << 5], v3 = Xf[(size_t)s3 << 5];
        float4 v4 = Xf[(size_t)s4 << 5], v5 = Xf[(size_t)s5 << 5];
        float4 v6 = Xf[(size_t)s6 << 5], v7 = Xf[(size_t)s7 << 5];
        A = f4add(A, v0); B = f4add(B, v1); C = f4add(C, v2); D = f4add(D, v3);
        A = f4add(A, v4); B = f4add(B, v5); C = f4add(C, v6); D = f4add(D, v7);
    }
    for (; p + 4 <= p1; p += 4) {
        int s0 = csr[p], s1 = csr[p + 1], s2 = csr[p + 2], s3 = csr[p + 3];
        float4 v0 = Xf[(size_t)s0 << 5], v1 = Xf[(size_t)s1 << 5];
        float4 v2 = Xf[(size_t)s2 << 5], v3 = Xf[(size_t)s3 << 5];
        A = f4add(A, v0); B = f4add(B, v1); C = f4add(C, v2); D = f4add(D, v3);
    }
    for (; p < p1; ++p) {
        int s = csr[p];
        A = f4add(A, Xf[(size_t)s << 5]);
    }
    float4 acc = f4add(f4add(A, B), f4add(C, D));
    acc = f4add(acc, Xf[(size_t)node << 5]);    // self term (prescaled)

    float dd = 1.0f / sqrtf((float)(p1 - p0) + 1.0f);
    float4 bb = *(const float4*)(bias + (lane << 2));
    acc.x = fmaxf(fmaf(acc.x, dd, bb.x), 0.f);
    acc.y = fmaxf(fmaf(acc.y, dd, bb.y), 0.f);
    acc.z = fmaxf(fmaf(acc.z, dd, bb.z), 0.f);
    acc.w = fmaxf(fmaf(acc.w, dd, bb.w), 0.f);
    *(float4*)(hout + ((size_t)node << 7) + (lane << 2)) = acc;

    float4 wsv = *(const float4*)(Ws + (lane << 2));
    float pq = acc.x * wsv.x + acc.y * wsv.y + acc.z * wsv.z + acc.w * wsv.w;
#pragma unroll
    for (int off = 16; off > 0; off >>= 1) pq += __shfl_down(pq, off, 32);
    if (lane == 0) hss[node] = dd * pq;         // prescaled score
}

// ---- fused score + top-k + (BUILD: level-2 CSR) + per-graph readout {max|mean} --------
template <int NNE, int KK, bool BUILD>
__global__ void sctopk_k(const int* __restrict__ rbeg, const int* __restrict__ rend,
                         const int* __restrict__ csr, const float* __restrict__ hss,
                         const float* __restrict__ bsp,
                         int* __restrict__ perm, float* __restrict__ tsel,
                         const int* __restrict__ src, const int* __restrict__ dst,
                         int* __restrict__ rbeg2, int* __restrict__ rend2,
                         int* __restrict__ csr2,
                         const float* __restrict__ h, float* __restrict__ xout)
{
    __shared__ unsigned long long keys[NNE];
    __shared__ float hl[NNE];
    __shared__ int   pix[KK];
    __shared__ float tsl[KK];
    int t = threadIdx.x;
    int g = xcd_swz(blockIdx.x, GG);
    int node = g * NNE + t;
    hl[t] = hss[node];
    __syncthreads();

    // ---- score: gather prescaled neighbor scores from LDS ----
    int p0 = rbeg[node], p1 = rend[node];
    float a = 0.f, b = 0.f, c = 0.f, e = 0.f;
    int p = p0;
    for (; p + 8 <= p1; p += 8) {
        int s0 = csr[p] & (NNE - 1), s1 = csr[p + 1] & (NNE - 1);
        int s2 = csr[p + 2] & (NNE - 1), s3 = csr[p + 3] & (NNE - 1);
        int s4 = csr[p + 4] & (NNE - 1), s5 = csr[p + 5] & (NNE - 1);
        int s6 = csr[p + 6] & (NNE - 1), s7 = csr[p + 7] & (NNE - 1);
        a += hl[s0]; b += hl[s1]; c += hl[s2]; e += hl[s3];
        a += hl[s4]; b += hl[s5]; c += hl[s6]; e += hl[s7];
    }
    for (; p + 4 <= p1; p += 4) {
        int s0 = csr[p] & (NNE - 1), s1 = csr[p + 1] & (NNE - 1);
        int s2 = csr[p + 2] & (NNE - 1), s3 = csr[p + 3] & (NNE - 1);
        a += hl[s0]; b += hl[s1]; c += hl[s2]; e += hl[s3];
    }
    for (; p < p1; ++p) a += hl[csr[p] & (NNE - 1)];
    float dd = 1.0f / sqrtf((float)(p1 - p0) + 1.0f);
    float s = fmaf((a + b) + (c + e) + hl[t], dd, bsp[0]);

    // ---- bitonic sort of (monotone score, NNE-1-idx): exact jax top_k tie-break ----
    unsigned u = __float_as_uint(s);
    u = (u & 0x80000000u) ? ~u : (u | 0x80000000u);
    __syncthreads();
    keys[t] = (((unsigned long long)u) << 32) | (unsigned)(NNE - 1 - t);
    __syncthreads();
    for (int k = 2; k <= NNE; k <<= 1) {
        for (int j = k >> 1; j > 0; j >>= 1) {
            int ixj = t ^ j;
            if (ixj > t) {
                unsigned long long ka = keys[t], kb = keys[ixj];
                bool up = ((t & k) == 0);
                if ((ka > kb) == up) { keys[t] = kb; keys[ixj] = ka; }
            }
            __syncthreads();
        }
    }
    unsigned long long key = keys[NNE - 1 - t];   // rank t
    int idx = NNE - 1 - (int)(key & 0xFFFFFFFFu);
    if (t < KK) {
        unsigned uu = (unsigned)(key >> 32);
        float sc = __uint_as_float((uu & 0x80000000u) ? (uu ^ 0x80000000u) : ~uu);
        float tv = tanhf(sc);
        pix[t] = g * NNE + idx;
        tsl[t] = tv;
        if (BUILD) {                   // level 1: gemm2 consumes these globally
            perm[g * KK + t] = g * NNE + idx;
            tsel[g * KK + t] = tv;
        }
    }

    if (BUILD) {
        constexpr int EPT = BUILD ? (EPG / NNE) : 1;
        __syncthreads();                       // all keys reads done -> regions reusable
        int* nml = (int*)hl;                   // local new-id map (NNE ints)
        int* cnt = (int*)keys;                 // KK counters
        nml[t] = -1;
        if (t < KK) cnt[t] = 0;
        __syncthreads();
        if (t < KK) nml[idx] = t;              // local rank of kept node
        __syncthreads();

        int ebase = g * EPG;
        int nsl[EPT], ndl[EPT];
#pragma unroll
        for (int k = 0; k < EPT; ++k) {
            int e = ebase + t + k * NNE;
            nsl[k] = nml[src[e] & (NNE - 1)];
            ndl[k] = nml[dst[e] & (NNE - 1)];
            if (nsl[k] >= 0 && ndl[k] >= 0) atomicAdd(&cnt[ndl[k]], 1);
        }
        __syncthreads();
        int deg0 = 0, val = 0;
        if (t < KK) { deg0 = cnt[t]; val = deg0; }
        for (int off = 1; off < KK; off <<= 1) {
            int u2 = (t < KK && t >= off) ? cnt[t - off] : 0;
            __syncthreads();
            if (t < KK) { val += u2; cnt[t] = val; }
            __syncthreads();
        }
        if (t < KK) {
            int n2 = g * KK + t;
            rbeg2[n2] = ebase + val - deg0;
            rend2[n2] = ebase + val;
            cnt[t] = val - deg0;
        }
        __syncthreads();
#pragma unroll
        for (int k = 0; k < EPT; ++k) {
            if (nsl[k] >= 0 && ndl[k] >= 0) {
                int pos = atomicAdd(&cnt[ndl[k]], 1);
                csr2[ebase + pos] = g * KK + nsl[k];
            }
        }
    }

    // ---- readout: x[g] = {col-max | col-mean} over KK kept rows of h*tanh ----
    constexpr int G = NNE / 128;               // row groups
    __syncthreads();                           // cnt/keys last use done
    float* rmax = (float*)keys;                // [G][128]
    float* rsum = rmax + G * 128;              // [G][128]  (2*G*128*4 == 8*NNE bytes)
    int col = t & 127;
    int grp = t >> 7;
    float mx = -INFINITY, sm = 0.f;
#pragma unroll 8
    for (int rr0 = 0; rr0 < KK / G; ++rr0) {
        int rr = grp + rr0 * G;
        int o = pix[rr];
        float tv = tsl[rr];
        float v = h[((size_t)o << 7) + col] * tv;
        mx = fmaxf(mx, v);
        sm += v;
    }
    rmax[grp * 128 + col] = mx;
    rsum[grp * 128 + col] = sm;
    __syncthreads();
    if (t < 128) {
        float m = rmax[t], s2 = rsum[t];
#pragma unroll
        for (int j2 = 1; j2 < G; ++j2) {
            m = fmaxf(m, rmax[j2 * 128 + t]);
            s2 += rsum[j2 * 128 + t];
        }
        xout[g * 256 + t] = m;
        xout[g * 256 + 128 + t] = s2 * (1.0f / (float)KK);
    }
}

// ---------------- head: z=x1+x2; relu(z@Wl1+bl1); @Wl2+bl2 ------------
__global__ __launch_bounds__(128) void mlp_k(const float* __restrict__ x1, const float* __restrict__ x2,
                                             const float* __restrict__ Wl1, const float* __restrict__ bl1,
                                             const float* __restrict__ Wl2, const float* __restrict__ bl2,
                                             float* __restrict__ out)
{
    __shared__ float z[256];
    __shared__ float red[128];
    int g = blockIdx.x, t = threadIdx.x;
    z[t]       = x1[g * 256 + t]       + x2[g * 256 + t];
    z[t + 128] = x1[g * 256 + 128 + t] + x2[g * 256 + 128 + t];
    __syncthreads();
    float acc = bl1[t];
    for (int k = 0; k < 256; ++k) acc = fmaf(z[k], Wl1[k * 128 + t], acc);
    float zz = fmaxf(acc, 0.f);
    red[t] = zz * Wl2[t];
    __syncthreads();
    for (int off = 64; off > 0; off >>= 1) {
        if (t < off) red[t] += red[t + off];
        __syncthreads();
    }
    if (t == 0) out[g] = red[0] + bl2[0];
}

// ---------------- launch ----------------
extern "C" void kernel_launch(void* const* d_in, const int* in_sizes, int n_in,
                              void* d_out, int out_size, void* d_ws, size_t ws_size,
                              hipStream_t stream)
{
    const float* x   = (const float*)d_in[0];
    const int*   src = (const int*)d_in[1];
    const int*   dst = (const int*)d_in[2];
    const float* W1  = (const float*)d_in[3];
    const float* b1  = (const float*)d_in[4];
    const float* Ws1 = (const float*)d_in[5];
    const float* bs1 = (const float*)d_in[6];
    const float* W2  = (const float*)d_in[7];
    const float* b2  = (const float*)d_in[8];
    const float* Ws2 = (const float*)d_in[9];
    const float* bs2 = (const float*)d_in[10];
    const float* Wl1 = (const float*)d_in[11];
    const float* bl1 = (const float*)d_in[12];
    const float* Wl2 = (const float*)d_in[13];
    const float* bl2 = (const float*)d_in[14];
    float* out = (float*)d_out;
    char* ws = (char*)d_ws;

    // big regions (time-multiplexed)
    float* XW1 = (float*)(ws);                        // 32MB [0,32M)   (dinv-prescaled)
    float* h1  = (float*)(ws + ((size_t)32 << 20));   // 32MB [32M,64M)
    float* XW2 = (float*)(ws);                        // 16MB [0,16M)   (XW1 dead after agg1)
    float* h2  = (float*)(ws + ((size_t)16 << 20));   // 16MB [16M,32M)
    size_t SB = (size_t)64 << 20;
    auto alloc = [&](size_t bytes) { char* p = ws + SB; SB += (bytes + 255) & ~(size_t)255; return p; };
    int* csr1     = (int*)alloc((size_t)EE * 4);      // reused as csr2 (in-block, race-free)
    int* rbeg1    = (int*)alloc(NN1 * 4);
    int* rend1    = (int*)alloc(NN1 * 4);
    float* hss1   = (float*)alloc(NN1 * 4);
    int* perm1    = (int*)alloc(M1 * 4);
    float* tsel1  = (float*)alloc(M1 * 4);
    int* rbeg2    = (int*)alloc(M1 * 4);
    int* rend2    = (int*)alloc(M1 * 4);
    float* hss2   = (float*)alloc(M1 * 4);
    float* x1b    = (float*)alloc(GG * 256 * 4);
    float* x2b    = (float*)alloc(GG * 256 * 4);
    int* csr2     = csr1;
    (void)ws_size; (void)in_sizes; (void)n_in; (void)out_size;

    // ---- level 1 ----
    build_csr1_k<<<GG, 1024, 0, stream>>>(src, dst, rbeg1, rend1, csr1);
    gemm1_k<<<NN1 / 128, 256, 0, stream>>>(x, W1, rbeg1, rend1, XW1);
    agg_feat_k<<<NN1 / 8, 256, 0, stream>>>((const float4*)XW1, rbeg1, rend1, csr1, b1, Ws1, h1, hss1, NN1);
    sctopk_k<NPG, K1, true><<<GG, NPG, 0, stream>>>(rbeg1, rend1, csr1, hss1, bs1, perm1, tsel1,
                                                    src, dst, rbeg2, rend2, csr2, h1, x1b);
    // ---- level 2 ----
    gemm2_k<<<M1 / 128, 256, 0, stream>>>(h1, W2, rbeg2, rend2, perm1, tsel1, XW2);
    agg_feat_k<<<M1 / 8, 256, 0, stream>>>((const float4*)XW2, rbeg2, rend2, csr2, b2, Ws2, h2, hss2, M1);
    sctopk_k<K1, K2, false><<<GG, K1, 0, stream>>>(rbeg2, rend2, csr2, hss2, bs2, nullptr, nullptr,
                                                   nullptr, nullptr, nullptr, nullptr, nullptr, h2, x2b);
    // ---- head ----
    mlp_k<<<GG, 128, 0, stream>>>(x1b, x2b, Wl1, bl1, Wl2, bl2, out);
}